// Round 24
// baseline (93.423 us; speedup 1.0000x reference)
//
#include <hip/hip_runtime.h>
#include <stdint.h>

#define NA    100800
#define NIMG  8
#define TOPK  2048
#define NBLK1 99              // ceil(NA / 1024)
#define SEGSTRIDE (NBLK1 * 1024)   // 101376 u64 per image (segmented cand)
typedef unsigned long long u64;

// ---------------- K1: filter -> per-block segmented keys + per-block count ----------------
// Block b writes its <=1024 keys to cand[m*SEGSTRIDE + b*1024 ..] and count to bcnt.
// Plain stores only: nothing needs pre-zeroing, no global atomics, no memset dispatch.
// Key order is arbitrary — harmless: k2_rank's counting-rank output is order-independent
// (unique full-u64 keys).
__global__ __launch_bounds__(256) void k1_scan(const float* __restrict__ pred,
                                               u64* __restrict__ cand,
                                               int* __restrict__ bcnt) {
    __shared__ u64 lkeys[1024];
    __shared__ int lcnt;
    int t = threadIdx.x;
    int m = blockIdx.y;
    int b = blockIdx.x;
    if (t == 0) lcnt = 0;
    __syncthreads();
    const float4* p4 = reinterpret_cast<const float4*>(pred + (size_t)m * NA * 16);
    int row0blk = b * 1024;
    for (int pass = 0; pass < 4; ++pass) {
        int row0 = row0blk + pass * 256;
        int i1 = row0 * 4 + 2 * t + 1;
        int i2 = i1 + 512;
        float4 A = make_float4(0.f, 0.f, 0.f, 0.f);
        float4 B = make_float4(0.f, 0.f, 0.f, 0.f);
        if ((i1 >> 2) < NA) A = p4[i1];
        if ((i2 >> 2) < NA) B = p4[i2];
        float aw = __shfl_xor(A.w, 1);          // x15 of row rA (valid on even lanes)
        float bw = __shfl_xor(B.w, 1);          // x15 of row rB
        if (!(t & 1)) {
            int rA = row0 + (t >> 1);
            int rB = rA + 128;
            {
                float obj = A.x, x15 = aw;
                if (rA < NA) {
                    float conf = __fmul_rn(x15, obj);   // exact ref op
                    if (obj > 0.5f && conf > 0.5f) {
                        unsigned cb = __float_as_uint(conf);
                        int p = atomicAdd(&lcnt, 1);
                        lkeys[p] = ((u64)cb << 32) | (u64)(0xFFFFFFFFu - (unsigned)rA);
                    }
                }
            }
            {
                float obj = B.x, x15 = bw;
                if (rB < NA) {
                    float conf = __fmul_rn(x15, obj);
                    if (obj > 0.5f && conf > 0.5f) {
                        unsigned cb = __float_as_uint(conf);
                        int p = atomicAdd(&lcnt, 1);
                        lkeys[p] = ((u64)cb << 32) | (u64)(0xFFFFFFFFu - (unsigned)rB);
                    }
                }
            }
        }
    }
    __syncthreads();
    if (t == 0) bcnt[m * NBLK1 + b] = lcnt;
    int n = lcnt;
    u64* cm = cand + (size_t)m * SEGSTRIDE + (size_t)b * 1024;
    for (int i = t; i < n; i += 256) cm[i] = lkeys[i];
}

// ---------------- K2: prefix(bcnt) + fine 4096-bin rank over ALL keys -> sel + boxes ----------------
// Pass 1: grid-stride over dense [0,M) (segment via 7-step LDS binary search on prefix P),
//         build fine 4096-bin histogram of ALL keys.
// Scan:   4096-bin prefix sum locates cutoff bin B* (prefix first reaching min(M,2048)).
// Pass 2: re-read keys (L2-hot), scatter bins <= B* into outb at exact fstart slots.
// Then per-bin insertion sort (unique u64 keys -> deterministic) + emit top-2048.
__global__ __launch_bounds__(1024) void k2_rank(const u64* __restrict__ cand,
                                                const int* __restrict__ bcnt,
                                                const float* __restrict__ pred,
                                                u64* __restrict__ sel,
                                                float4* __restrict__ boxes) {
    __shared__ int fcnt[4096];
    __shared__ int fstart[4096];
    __shared__ u64 outb[4096];
    __shared__ int wsum[16];
    __shared__ int P[100];
    __shared__ int bstar_sh, toplim_sh;
    int m = blockIdx.x, t = threadIdx.x;
    int lane = t & 63, w = t >> 6;
    if (t == 0) { bstar_sh = -1; toplim_sh = 0; }
    #pragma unroll
    for (int r = 0; r < 4; ++r) { fcnt[t + r * 1024] = 0; outb[t + r * 1024] = 0ull; }
    __syncthreads();
    // ---- prefix over 99 per-block counts (wave 0; bcnt loaded once, coalesced) ----
    if (w == 0) {
        const int* bb = bcnt + m * NBLK1;
        int s1 = bb[lane];                       // segments 0..63
        #pragma unroll
        for (int off = 1; off < 64; off <<= 1) {
            int u = __shfl_up(s1, off);
            if (lane >= off) s1 += u;
        }
        P[lane + 1] = s1;                        // P[1..64]
        if (lane == 0) P[0] = 0;
        int tot1 = __shfl(s1, 63);
        int s2 = (lane < 35) ? bb[64 + lane] : 0; // segments 64..98
        #pragma unroll
        for (int off = 1; off < 64; off <<= 1) {
            int u = __shfl_up(s2, off);
            if (lane >= off) s2 += u;
        }
        if (lane < 35) P[65 + lane] = s2 + tot1; // P[65..99]
    }
    __syncthreads();
    int M = P[99];
    int need = min(M, TOPK);
    // ---- pass 1: fine histogram of all keys ----
    for (int d = t; d < M; d += 1024) {
        int lo = 0, hi = 99;                     // invariant: P[lo] <= d < P[hi]
        #pragma unroll
        for (int it = 0; it < 7; ++it) {
            int mid = (lo + hi) >> 1;
            if (P[mid] <= d) lo = mid; else hi = mid;
        }
        u64 key = cand[(size_t)m * SEGSTRIDE + (size_t)lo * 1024 + (d - P[lo])];
        int rb = 4095 - (int)(((unsigned)(key >> 32) - 0x3F000000u) >> 11);
        atomicAdd(&fcnt[rb], 1);
    }
    __syncthreads();
    // ---- 4096-bin exclusive prefix sum (thread t owns bins 4t..4t+3) + find B* ----
    int c0 = fcnt[4 * t], c1 = fcnt[4 * t + 1], c2 = fcnt[4 * t + 2], c3 = fcnt[4 * t + 3];
    int s = c0 + c1 + c2 + c3;
    int incl = s;
    #pragma unroll
    for (int off = 1; off < 64; off <<= 1) {
        int v = __shfl_up(incl, off);
        if (lane >= off) incl += v;
    }
    if (lane == 63) wsum[w] = incl;
    __syncthreads();
    if (w == 0) {
        int v = (lane < 16) ? wsum[lane] : 0;
        #pragma unroll
        for (int off = 1; off < 16; off <<= 1) {
            int u = __shfl_up(v, off);
            if (lane >= off) v += u;
        }
        if (lane < 16) wsum[lane] = v;           // inclusive wave sums
    }
    __syncthreads();
    int base = (w > 0 ? wsum[w - 1] : 0) + (incl - s);
    int e0 = base + c0, e1 = e0 + c1, e2 = e1 + c2, e3 = e2 + c3;
    fstart[4 * t]     = base;
    fstart[4 * t + 1] = e0;
    fstart[4 * t + 2] = e1;
    fstart[4 * t + 3] = e2;
    if (need > 0) {                              // exactly one bin satisfies
        if (base < need && e0 >= need) { bstar_sh = 4 * t;     toplim_sh = min(e0, 4096); }
        if (e0   < need && e1 >= need) { bstar_sh = 4 * t + 1; toplim_sh = min(e1, 4096); }
        if (e1   < need && e2 >= need) { bstar_sh = 4 * t + 2; toplim_sh = min(e2, 4096); }
        if (e2   < need && e3 >= need) { bstar_sh = 4 * t + 3; toplim_sh = min(e3, 4096); }
    }
    __syncthreads();
    int bstar = bstar_sh, toplim = toplim_sh;
    // ---- pass 2: scatter keys of bins <= B* (re-read; L2-hot) ----
    for (int d = t; d < M; d += 1024) {
        int lo = 0, hi = 99;
        #pragma unroll
        for (int it = 0; it < 7; ++it) {
            int mid = (lo + hi) >> 1;
            if (P[mid] <= d) lo = mid; else hi = mid;
        }
        u64 key = cand[(size_t)m * SEGSTRIDE + (size_t)lo * 1024 + (d - P[lo])];
        int rb = 4095 - (int)(((unsigned)(key >> 32) - 0x3F000000u) >> 11);
        if (rb <= bstar) {
            int old = atomicSub(&fcnt[rb], 1);
            int slot = fstart[rb] + old - 1;
            if (slot < 4096) outb[slot] = key;
        }
    }
    __syncthreads();
    // ---- per-bin insertion sort desc (bins <= B* only; deterministic cleanup) ----
    #pragma unroll
    for (int r = 0; r < 4; ++r) {
        int b = t + r * 1024;
        if (b <= bstar) {
            int st = fstart[b];
            int en = (b < bstar) ? fstart[b + 1] : toplim;
            if (en > 4096) en = 4096;
            for (int x = st + 1; x < en; ++x) {
                u64 key = outb[x];
                int y = x - 1;
                while (y >= st && outb[y] < key) { outb[y + 1] = outb[y]; --y; }
                outb[y + 1] = key;
            }
        }
    }
    __syncthreads();
    // ---- emit sel + staged xyxy boxes for top-2048 ----
    #pragma unroll
    for (int r = 0; r < 2; ++r) {
        int i = t + r * 1024;
        u64 key = outb[i];
        sel[(size_t)m * TOPK + i] = key;
        float4 b = make_float4(0.f, 0.f, 0.f, 0.f);
        if (key) {
            unsigned idx = 0xFFFFFFFFu - (unsigned)(key & 0xFFFFFFFFull);
            const float4* rv = reinterpret_cast<const float4*>(pred + ((size_t)m * NA + idx) * 16);
            float4 v = rv[0];                   // [xc, yc, w, h]
            float hw = __fmul_rn(v.z, 0.5f), hh = __fmul_rn(v.w, 0.5f);
            b.x = __fsub_rn(v.x, hw);
            b.y = __fsub_rn(v.y, hh);
            b.z = __fadd_rn(v.x, hw);
            b.w = __fadd_rn(v.y, hh);
        }
        boxes[(size_t)m * TOPK + i] = b;
    }
}

// ---------------- K4: 2048x2048 suppression bitmask, TRANSPOSED (iou > 0.45) ----------------
__global__ __launch_bounds__(1024) void k4_masks(const float4* __restrict__ boxes,
                                                 u64* __restrict__ maskT) {
    __shared__ float4 bx[TOPK];
    int m   = blockIdx.y;
    int grp = blockIdx.x;                       // 64 groups of 32 rows
    for (int i = threadIdx.x; i < TOPK; i += 1024)
        bx[i] = boxes[(size_t)m * TOPK + i];
    __syncthreads();

    int il = threadIdx.x & 31;
    int w  = threadIdx.x >> 5;
    int i  = grp * 32 + il;
    float4 b1 = bx[i];
    float a1 = __fmul_rn(__fsub_rn(b1.z, b1.x), __fsub_rn(b1.w, b1.y));
    u64 bits = 0ull;
    #pragma unroll 4
    for (int jj = 0; jj < 64; ++jj) {
        float4 b2 = bx[w * 64 + jj];
        float a2 = __fmul_rn(__fsub_rn(b2.z, b2.x), __fsub_rn(b2.w, b2.y));
        float iw = fmaxf(__fsub_rn(fminf(b1.z, b2.z), fmaxf(b1.x, b2.x)), 0.f);
        float ih = fmaxf(__fsub_rn(fminf(b1.w, b2.w), fmaxf(b1.y, b2.y)), 0.f);
        float inter = __fmul_rn(iw, ih);
        float uni   = __fsub_rn(__fadd_rn(a1, a2), inter);   // (a1+a2)-inter, ref order
        float iou   = __fdiv_rn(inter, uni);
        if (iou > 0.45f) bits |= (1ull << jj);
    }
    maskT[((size_t)m * 32 + w) * 2048 + i] = bits;
}

// ---------------- K5: batched-MIS scan + PREFETCHED update waves + fused output ----------------
__global__ __launch_bounds__(1024) void k5_nms(const u64* __restrict__ sel,
                                               const u64* __restrict__ maskT,
                                               const float* __restrict__ pred,
                                               float4* __restrict__ out) {
    __shared__ u64 remv[32];
    __shared__ u64 kbshare[2];
    __shared__ u64 kws[32];
    int m = blockIdx.x;
    int t = threadIdx.x;
    int lane = t & 63;
    int wv = t >> 6;                            // wave id 0..15
    const u64* mt = maskT + (size_t)m * 32 * 2048;
    if (t < 32) remv[t] = 0ull;
    u64 dval = 0ull, sval = 0ull, tval = 0ull;
    u64 cfmask = 0ull;
    u64 mybit = 1ull << lane;
    u64 lowmask = mybit - 1ull;
    if (wv == 0) {
        dval = mt[(size_t)0 * 2048 + lane];
        sval = sel[(size_t)m * TOPK + lane];
        tval = mt[(size_t)0 * 2048 + 64 + lane];
    }
    __syncthreads();

    u64 uA1 = 0ull, uA2 = 0ull, uB1 = 0ull, uB2 = 0ull;

#define K5_SCAN(B) do {                                                       \
    u64 dn = 0ull, sn = 0ull, tn = 0ull;                                      \
    if ((B) < 31) {                                                           \
        int r = ((B) + 1) * 64 + lane;                                        \
        dn = mt[(size_t)((B) + 1) * 2048 + r];                                \
        sn = sel[(size_t)m * TOPK + r];                                       \
        if ((B) < 30) tn = mt[(size_t)((B) + 1) * 2048 + r + 64];             \
    }                                                                         \
    u64 ext = remv[(B)];                                                      \
    u64 validw = __ballot(sval != 0ull);                                      \
    u64 alive = validw & ~ext & ~cfmask;                                      \
    u64 kb = 0ull;                                                            \
    while (alive) {                                                           \
        u64 c = dval & alive & lowmask;                                       \
        u64 ready = __ballot(((alive & mybit) != 0ull) && (c == 0ull));       \
        kb |= ready;                                                          \
        u64 removed = __ballot((dval & ready) != 0ull);                       \
        alive &= ~(ready | removed);                                          \
    }                                                                         \
    cfmask = ((B) < 31) ? __ballot((tval & kb) != 0ull) : 0ull;               \
    if (lane == 0) { kbshare[(B) & 1] = kb; kws[(B)] = kb; }                  \
    dval = dn; sval = sn; tval = tn;                                          \
} while (0)

#define K5_UP_ISSUE(V1, V2, S) do {  /* loads consumed at step (S) */         \
    int w1_ = (S) + wv, w2_ = (S) + 15 + wv;                                  \
    V1 = (w1_ < 32) ? mt[(size_t)((S) - 1) * 2048 + w1_ * 64 + lane] : 0ull;  \
    V2 = (w2_ < 32) ? mt[(size_t)((S) - 1) * 2048 + w2_ * 64 + lane] : 0ull;  \
} while (0)

#define K5_UP_CONSUME(V1, V2, B) do {                                         \
    u64 kb = kbshare[((B) - 1) & 1];                                          \
    int w1_ = (B) + wv, w2_ = (B) + 15 + wv;                                  \
    u64 c1 = __ballot((V1 & kb) != 0ull);                                     \
    u64 c2 = __ballot((V2 & kb) != 0ull);                                     \
    if (w1_ < 32 && lane == 0) remv[w1_] |= c1;                               \
    if (w2_ < 32 && lane == 0) remv[w2_] |= c2;                               \
} while (0)

    #pragma unroll 1
    for (int it = 0; it < 16; ++it) {
        int b0 = 2 * it, b1 = b0 + 1;
        if (wv == 0) {
            K5_SCAN(b0);
        } else {
            K5_UP_ISSUE(uB1, uB2, b0 + 1);      // for consumption at step b1
            if (b0 >= 1) K5_UP_CONSUME(uA1, uA2, b0);
        }
        __syncthreads();
        if (wv == 0) {
            K5_SCAN(b1);
        } else {
            if (b1 + 1 < 32) K5_UP_ISSUE(uA1, uA2, b1 + 1); // for next iteration's b0
            K5_UP_CONSUME(uB1, uB2, b1);
        }
        __syncthreads();
    }
#undef K5_SCAN
#undef K5_UP_ISSUE
#undef K5_UP_CONSUME

    // fused output write
    const u64* sl = sel + (size_t)m * TOPK;
    float4* om = out + (size_t)m * TOPK * 4;
    #pragma unroll
    for (int q = t; q < TOPK * 4; q += 1024) {
        int c4 = q & 3;
        int r  = q >> 2;
        float4 o = make_float4(0.f, 0.f, 0.f, 0.f);
        if ((kws[r >> 6] >> (r & 63)) & 1ull) {
            u64 key = sl[r];
            unsigned idx = 0xFFFFFFFFu - (unsigned)(key & 0xFFFFFFFFull);
            const float4* rv = reinterpret_cast<const float4*>(pred + ((size_t)m * NA + idx) * 16);
            float4 v = rv[c4];
            if (c4 == 0) {
                float hw = __fmul_rn(v.z, 0.5f), hh = __fmul_rn(v.w, 0.5f);
                o = make_float4(__fsub_rn(v.x, hw), __fsub_rn(v.y, hh),
                                __fadd_rn(v.x, hw), __fadd_rn(v.y, hh));
            } else if (c4 == 1) {
                o = make_float4(__uint_as_float((unsigned)(key >> 32)), v.y, v.z, v.w);
            } else if (c4 == 2) {
                o = v;
            } else {
                o = make_float4(v.x, v.y, v.z, 0.f);
            }
        }
        om[q] = o;
    }
}

// ---------------- launch ----------------
extern "C" void kernel_launch(void* const* d_in, const int* in_sizes, int n_in,
                              void* d_out, int out_size, void* d_ws, size_t ws_size,
                              hipStream_t stream) {
    (void)in_sizes; (void)n_in; (void)out_size; (void)ws_size;
    const float* pred = (const float*)d_in[0];
    char* ws = (char*)d_ws;
    // layout (bytes):
    u64*      cand     = (u64*)     (ws + 0);          // 8*101376*8 = 6,488,064
    u64*      sel      = (u64*)     (ws + 6488064);    // 8*2048*8   =   131,072
    float4*   boxes    = (float4*)  (ws + 6619136);    // 8*2048*16  =   262,144
    u64*      maskT    = (u64*)     (ws + 6881280);    // 8*32*2048*8= 4,194,304
    int*      bcnt     = (int*)     (ws + 11075584);   // 8*99*4     =     3,168
    float4*   out      = (float4*)d_out;

    hipLaunchKernelGGL(k1_scan,  dim3(NBLK1, NIMG), dim3(256),  0, stream, pred, cand, bcnt);
    hipLaunchKernelGGL(k2_rank,  dim3(NIMG),        dim3(1024), 0, stream, cand, bcnt, pred, sel, boxes);
    hipLaunchKernelGGL(k4_masks, dim3(64, NIMG),    dim3(1024), 0, stream, boxes, maskT);
    hipLaunchKernelGGL(k5_nms,   dim3(NIMG),        dim3(1024), 0, stream, sel, maskT, pred, out);
}

// Round 25
// 93.136 us; speedup vs baseline: 1.0031x; 1.0031x over previous
//
#include <hip/hip_runtime.h>
#include <stdint.h>

#define NA    100800
#define NIMG  8
#define TOPK  2048
#define NBLK1 99              // ceil(NA / 1024)
#define SEGSTRIDE (NBLK1 * 1024)   // 101376 u64 per image (segmented cand)
typedef unsigned long long u64;

// ---------------- K1: filter -> per-block segmented keys + per-block count ----------------
__global__ __launch_bounds__(256) void k1_scan(const float* __restrict__ pred,
                                               u64* __restrict__ cand,
                                               int* __restrict__ bcnt) {
    __shared__ u64 lkeys[1024];
    __shared__ int lcnt;
    int t = threadIdx.x;
    int m = blockIdx.y;
    int b = blockIdx.x;
    if (t == 0) lcnt = 0;
    __syncthreads();
    const float4* p4 = reinterpret_cast<const float4*>(pred + (size_t)m * NA * 16);
    int row0blk = b * 1024;
    for (int pass = 0; pass < 4; ++pass) {
        int row0 = row0blk + pass * 256;
        int i1 = row0 * 4 + 2 * t + 1;
        int i2 = i1 + 512;
        float4 A = make_float4(0.f, 0.f, 0.f, 0.f);
        float4 B = make_float4(0.f, 0.f, 0.f, 0.f);
        if ((i1 >> 2) < NA) A = p4[i1];
        if ((i2 >> 2) < NA) B = p4[i2];
        float aw = __shfl_xor(A.w, 1);          // x15 of row rA (valid on even lanes)
        float bw = __shfl_xor(B.w, 1);          // x15 of row rB
        if (!(t & 1)) {
            int rA = row0 + (t >> 1);
            int rB = rA + 128;
            {
                float obj = A.x, x15 = aw;
                if (rA < NA) {
                    float conf = __fmul_rn(x15, obj);   // exact ref op
                    if (obj > 0.5f && conf > 0.5f) {
                        unsigned cb = __float_as_uint(conf);
                        int p = atomicAdd(&lcnt, 1);
                        lkeys[p] = ((u64)cb << 32) | (u64)(0xFFFFFFFFu - (unsigned)rA);
                    }
                }
            }
            {
                float obj = B.x, x15 = bw;
                if (rB < NA) {
                    float conf = __fmul_rn(x15, obj);
                    if (obj > 0.5f && conf > 0.5f) {
                        unsigned cb = __float_as_uint(conf);
                        int p = atomicAdd(&lcnt, 1);
                        lkeys[p] = ((u64)cb << 32) | (u64)(0xFFFFFFFFu - (unsigned)rB);
                    }
                }
            }
        }
    }
    __syncthreads();
    if (t == 0) bcnt[m * NBLK1 + b] = lcnt;
    int n = lcnt;
    u64* cm = cand + (size_t)m * SEGSTRIDE + (size_t)b * 1024;
    for (int i = t; i < n; i += 256) cm[i] = lkeys[i];
}

// ---------------- K2: prefix(bcnt) + fine 4096-bin rank over ALL keys -> sel + boxes ----------------
__global__ __launch_bounds__(1024) void k2_rank(const u64* __restrict__ cand,
                                                const int* __restrict__ bcnt,
                                                const float* __restrict__ pred,
                                                u64* __restrict__ sel,
                                                float4* __restrict__ boxes) {
    __shared__ int fcnt[4096];
    __shared__ int fstart[4096];
    __shared__ u64 outb[4096];
    __shared__ int wsum[16];
    __shared__ int P[100];
    __shared__ int bstar_sh, toplim_sh;
    int m = blockIdx.x, t = threadIdx.x;
    int lane = t & 63, w = t >> 6;
    if (t == 0) { bstar_sh = -1; toplim_sh = 0; }
    #pragma unroll
    for (int r = 0; r < 4; ++r) { fcnt[t + r * 1024] = 0; outb[t + r * 1024] = 0ull; }
    __syncthreads();
    // ---- prefix over 99 per-block counts (wave 0; bcnt loaded once, coalesced) ----
    if (w == 0) {
        const int* bb = bcnt + m * NBLK1;
        int s1 = bb[lane];                       // segments 0..63
        #pragma unroll
        for (int off = 1; off < 64; off <<= 1) {
            int u = __shfl_up(s1, off);
            if (lane >= off) s1 += u;
        }
        P[lane + 1] = s1;                        // P[1..64]
        if (lane == 0) P[0] = 0;
        int tot1 = __shfl(s1, 63);
        int s2 = (lane < 35) ? bb[64 + lane] : 0; // segments 64..98
        #pragma unroll
        for (int off = 1; off < 64; off <<= 1) {
            int u = __shfl_up(s2, off);
            if (lane >= off) s2 += u;
        }
        if (lane < 35) P[65 + lane] = s2 + tot1; // P[65..99]
    }
    __syncthreads();
    int M = P[99];
    int need = min(M, TOPK);
    // ---- pass 1: fine histogram of all keys ----
    for (int d = t; d < M; d += 1024) {
        int lo = 0, hi = 99;                     // invariant: P[lo] <= d < P[hi]
        #pragma unroll
        for (int it = 0; it < 7; ++it) {
            int mid = (lo + hi) >> 1;
            if (P[mid] <= d) lo = mid; else hi = mid;
        }
        u64 key = cand[(size_t)m * SEGSTRIDE + (size_t)lo * 1024 + (d - P[lo])];
        int rb = 4095 - (int)(((unsigned)(key >> 32) - 0x3F000000u) >> 11);
        atomicAdd(&fcnt[rb], 1);
    }
    __syncthreads();
    // ---- 4096-bin exclusive prefix sum (thread t owns bins 4t..4t+3) + find B* ----
    int c0 = fcnt[4 * t], c1 = fcnt[4 * t + 1], c2 = fcnt[4 * t + 2], c3 = fcnt[4 * t + 3];
    int s = c0 + c1 + c2 + c3;
    int incl = s;
    #pragma unroll
    for (int off = 1; off < 64; off <<= 1) {
        int v = __shfl_up(incl, off);
        if (lane >= off) incl += v;
    }
    if (lane == 63) wsum[w] = incl;
    __syncthreads();
    if (w == 0) {
        int v = (lane < 16) ? wsum[lane] : 0;
        #pragma unroll
        for (int off = 1; off < 16; off <<= 1) {
            int u = __shfl_up(v, off);
            if (lane >= off) v += u;
        }
        if (lane < 16) wsum[lane] = v;           // inclusive wave sums
    }
    __syncthreads();
    int base = (w > 0 ? wsum[w - 1] : 0) + (incl - s);
    int e0 = base + c0, e1 = e0 + c1, e2 = e1 + c2, e3 = e2 + c3;
    fstart[4 * t]     = base;
    fstart[4 * t + 1] = e0;
    fstart[4 * t + 2] = e1;
    fstart[4 * t + 3] = e2;
    if (need > 0) {                              // exactly one bin satisfies
        if (base < need && e0 >= need) { bstar_sh = 4 * t;     toplim_sh = min(e0, 4096); }
        if (e0   < need && e1 >= need) { bstar_sh = 4 * t + 1; toplim_sh = min(e1, 4096); }
        if (e1   < need && e2 >= need) { bstar_sh = 4 * t + 2; toplim_sh = min(e2, 4096); }
        if (e2   < need && e3 >= need) { bstar_sh = 4 * t + 3; toplim_sh = min(e3, 4096); }
    }
    __syncthreads();
    int bstar = bstar_sh, toplim = toplim_sh;
    // ---- pass 2: scatter keys of bins <= B* (re-read; L2-hot) ----
    for (int d = t; d < M; d += 1024) {
        int lo = 0, hi = 99;
        #pragma unroll
        for (int it = 0; it < 7; ++it) {
            int mid = (lo + hi) >> 1;
            if (P[mid] <= d) lo = mid; else hi = mid;
        }
        u64 key = cand[(size_t)m * SEGSTRIDE + (size_t)lo * 1024 + (d - P[lo])];
        int rb = 4095 - (int)(((unsigned)(key >> 32) - 0x3F000000u) >> 11);
        if (rb <= bstar) {
            int old = atomicSub(&fcnt[rb], 1);
            int slot = fstart[rb] + old - 1;
            if (slot < 4096) outb[slot] = key;
        }
    }
    __syncthreads();
    // ---- per-bin insertion sort desc (bins <= B* only; deterministic cleanup) ----
    #pragma unroll
    for (int r = 0; r < 4; ++r) {
        int b = t + r * 1024;
        if (b <= bstar) {
            int st = fstart[b];
            int en = (b < bstar) ? fstart[b + 1] : toplim;
            if (en > 4096) en = 4096;
            for (int x = st + 1; x < en; ++x) {
                u64 key = outb[x];
                int y = x - 1;
                while (y >= st && outb[y] < key) { outb[y + 1] = outb[y]; --y; }
                outb[y + 1] = key;
            }
        }
    }
    __syncthreads();
    // ---- emit sel + staged xyxy boxes for top-2048 ----
    #pragma unroll
    for (int r = 0; r < 2; ++r) {
        int i = t + r * 1024;
        u64 key = outb[i];
        sel[(size_t)m * TOPK + i] = key;
        float4 b = make_float4(0.f, 0.f, 0.f, 0.f);
        if (key) {
            unsigned idx = 0xFFFFFFFFu - (unsigned)(key & 0xFFFFFFFFull);
            const float4* rv = reinterpret_cast<const float4*>(pred + ((size_t)m * NA + idx) * 16);
            float4 v = rv[0];                   // [xc, yc, w, h]
            float hw = __fmul_rn(v.z, 0.5f), hh = __fmul_rn(v.w, 0.5f);
            b.x = __fsub_rn(v.x, hw);
            b.y = __fsub_rn(v.y, hh);
            b.z = __fadd_rn(v.x, hw);
            b.w = __fadd_rn(v.y, hh);
        }
        boxes[(size_t)m * TOPK + i] = b;
    }
}

// ---------------- K4: suppression bitmask, TRANSPOSED, LOWER-TRIANGLE ONLY ----------------
// k5 only ever reads entries with word w <= row>>6 (diag: w==row>>6; tval: w==row>>6-1;
// lagged updates: w==S-1 <= row>>6-1). Skip computing/storing the strict upper triangle.
// LDS staging covers boxes [0, ((grp>>1)+1)*64) — exactly the referenced range:
// own rows i=grp*32+il <= grp*32+31 < limit; b2 rows w*64+jj <= (grp>>1)*64+63 < limit.
__global__ __launch_bounds__(1024) void k4_masks(const float4* __restrict__ boxes,
                                                 u64* __restrict__ maskT) {
    __shared__ float4 bx[TOPK];
    int m   = blockIdx.y;
    int grp = blockIdx.x;                       // 64 groups of 32 rows
    int nload = ((grp >> 1) + 1) * 64;
    for (int i = threadIdx.x; i < nload; i += 1024)
        bx[i] = boxes[(size_t)m * TOPK + i];
    __syncthreads();

    int il = threadIdx.x & 31;
    int w  = threadIdx.x >> 5;
    if (w > (grp >> 1)) return;                 // upper triangle: never read by k5
    int i  = grp * 32 + il;
    float4 b1 = bx[i];
    float a1 = __fmul_rn(__fsub_rn(b1.z, b1.x), __fsub_rn(b1.w, b1.y));
    u64 bits = 0ull;
    #pragma unroll 4
    for (int jj = 0; jj < 64; ++jj) {
        float4 b2 = bx[w * 64 + jj];
        float a2 = __fmul_rn(__fsub_rn(b2.z, b2.x), __fsub_rn(b2.w, b2.y));
        float iw = fmaxf(__fsub_rn(fminf(b1.z, b2.z), fmaxf(b1.x, b2.x)), 0.f);
        float ih = fmaxf(__fsub_rn(fminf(b1.w, b2.w), fmaxf(b1.y, b2.y)), 0.f);
        float inter = __fmul_rn(iw, ih);
        float uni   = __fsub_rn(__fadd_rn(a1, a2), inter);   // (a1+a2)-inter, ref order
        float iou   = __fdiv_rn(inter, uni);
        if (iou > 0.45f) bits |= (1ull << jj);
    }
    maskT[((size_t)m * 32 + w) * 2048 + i] = bits;
}

// ---------------- K5: batched-MIS scan + PREFETCHED update waves + fused output ----------------
__global__ __launch_bounds__(1024) void k5_nms(const u64* __restrict__ sel,
                                               const u64* __restrict__ maskT,
                                               const float* __restrict__ pred,
                                               float4* __restrict__ out) {
    __shared__ u64 remv[32];
    __shared__ u64 kbshare[2];
    __shared__ u64 kws[32];
    int m = blockIdx.x;
    int t = threadIdx.x;
    int lane = t & 63;
    int wv = t >> 6;                            // wave id 0..15
    const u64* mt = maskT + (size_t)m * 32 * 2048;
    if (t < 32) remv[t] = 0ull;
    u64 dval = 0ull, sval = 0ull, tval = 0ull;
    u64 cfmask = 0ull;
    u64 mybit = 1ull << lane;
    u64 lowmask = mybit - 1ull;
    if (wv == 0) {
        dval = mt[(size_t)0 * 2048 + lane];
        sval = sel[(size_t)m * TOPK + lane];
        tval = mt[(size_t)0 * 2048 + 64 + lane];
    }
    __syncthreads();

    u64 uA1 = 0ull, uA2 = 0ull, uB1 = 0ull, uB2 = 0ull;

#define K5_SCAN(B) do {                                                       \
    u64 dn = 0ull, sn = 0ull, tn = 0ull;                                      \
    if ((B) < 31) {                                                           \
        int r = ((B) + 1) * 64 + lane;                                        \
        dn = mt[(size_t)((B) + 1) * 2048 + r];                                \
        sn = sel[(size_t)m * TOPK + r];                                       \
        if ((B) < 30) tn = mt[(size_t)((B) + 1) * 2048 + r + 64];             \
    }                                                                         \
    u64 ext = remv[(B)];                                                      \
    u64 validw = __ballot(sval != 0ull);                                      \
    u64 alive = validw & ~ext & ~cfmask;                                      \
    u64 kb = 0ull;                                                            \
    while (alive) {                                                           \
        u64 c = dval & alive & lowmask;                                       \
        u64 ready = __ballot(((alive & mybit) != 0ull) && (c == 0ull));       \
        kb |= ready;                                                          \
        u64 removed = __ballot((dval & ready) != 0ull);                       \
        alive &= ~(ready | removed);                                          \
    }                                                                         \
    cfmask = ((B) < 31) ? __ballot((tval & kb) != 0ull) : 0ull;               \
    if (lane == 0) { kbshare[(B) & 1] = kb; kws[(B)] = kb; }                  \
    dval = dn; sval = sn; tval = tn;                                          \
} while (0)

#define K5_UP_ISSUE(V1, V2, S) do {  /* loads consumed at step (S) */         \
    int w1_ = (S) + wv, w2_ = (S) + 15 + wv;                                  \
    V1 = (w1_ < 32) ? mt[(size_t)((S) - 1) * 2048 + w1_ * 64 + lane] : 0ull;  \
    V2 = (w2_ < 32) ? mt[(size_t)((S) - 1) * 2048 + w2_ * 64 + lane] : 0ull;  \
} while (0)

#define K5_UP_CONSUME(V1, V2, B) do {                                         \
    u64 kb = kbshare[((B) - 1) & 1];                                          \
    int w1_ = (B) + wv, w2_ = (B) + 15 + wv;                                  \
    u64 c1 = __ballot((V1 & kb) != 0ull);                                     \
    u64 c2 = __ballot((V2 & kb) != 0ull);                                     \
    if (w1_ < 32 && lane == 0) remv[w1_] |= c1;                               \
    if (w2_ < 32 && lane == 0) remv[w2_] |= c2;                               \
} while (0)

    #pragma unroll 1
    for (int it = 0; it < 16; ++it) {
        int b0 = 2 * it, b1 = b0 + 1;
        if (wv == 0) {
            K5_SCAN(b0);
        } else {
            K5_UP_ISSUE(uB1, uB2, b0 + 1);      // for consumption at step b1
            if (b0 >= 1) K5_UP_CONSUME(uA1, uA2, b0);
        }
        __syncthreads();
        if (wv == 0) {
            K5_SCAN(b1);
        } else {
            if (b1 + 1 < 32) K5_UP_ISSUE(uA1, uA2, b1 + 1); // for next iteration's b0
            K5_UP_CONSUME(uB1, uB2, b1);
        }
        __syncthreads();
    }
#undef K5_SCAN
#undef K5_UP_ISSUE
#undef K5_UP_CONSUME

    // fused output write
    const u64* sl = sel + (size_t)m * TOPK;
    float4* om = out + (size_t)m * TOPK * 4;
    #pragma unroll
    for (int q = t; q < TOPK * 4; q += 1024) {
        int c4 = q & 3;
        int r  = q >> 2;
        float4 o = make_float4(0.f, 0.f, 0.f, 0.f);
        if ((kws[r >> 6] >> (r & 63)) & 1ull) {
            u64 key = sl[r];
            unsigned idx = 0xFFFFFFFFu - (unsigned)(key & 0xFFFFFFFFull);
            const float4* rv = reinterpret_cast<const float4*>(pred + ((size_t)m * NA + idx) * 16);
            float4 v = rv[c4];
            if (c4 == 0) {
                float hw = __fmul_rn(v.z, 0.5f), hh = __fmul_rn(v.w, 0.5f);
                o = make_float4(__fsub_rn(v.x, hw), __fsub_rn(v.y, hh),
                                __fadd_rn(v.x, hw), __fadd_rn(v.y, hh));
            } else if (c4 == 1) {
                o = make_float4(__uint_as_float((unsigned)(key >> 32)), v.y, v.z, v.w);
            } else if (c4 == 2) {
                o = v;
            } else {
                o = make_float4(v.x, v.y, v.z, 0.f);
            }
        }
        om[q] = o;
    }
}

// ---------------- launch ----------------
extern "C" void kernel_launch(void* const* d_in, const int* in_sizes, int n_in,
                              void* d_out, int out_size, void* d_ws, size_t ws_size,
                              hipStream_t stream) {
    (void)in_sizes; (void)n_in; (void)out_size; (void)ws_size;
    const float* pred = (const float*)d_in[0];
    char* ws = (char*)d_ws;
    // layout (bytes):
    u64*      cand     = (u64*)     (ws + 0);          // 8*101376*8 = 6,488,064
    u64*      sel      = (u64*)     (ws + 6488064);    // 8*2048*8   =   131,072
    float4*   boxes    = (float4*)  (ws + 6619136);    // 8*2048*16  =   262,144
    u64*      maskT    = (u64*)     (ws + 6881280);    // 8*32*2048*8= 4,194,304
    int*      bcnt     = (int*)     (ws + 11075584);   // 8*99*4     =     3,168
    float4*   out      = (float4*)d_out;

    hipLaunchKernelGGL(k1_scan,  dim3(NBLK1, NIMG), dim3(256),  0, stream, pred, cand, bcnt);
    hipLaunchKernelGGL(k2_rank,  dim3(NIMG),        dim3(1024), 0, stream, cand, bcnt, pred, sel, boxes);
    hipLaunchKernelGGL(k4_masks, dim3(64, NIMG),    dim3(1024), 0, stream, boxes, maskT);
    hipLaunchKernelGGL(k5_nms,   dim3(NIMG),        dim3(1024), 0, stream, sel, maskT, pred, out);
}